// Round 2
// baseline (481.806 us; speedup 1.0000x reference)
//
#include <hip/hip_runtime.h>

#define NB 2000000
#define BLOCK 256
#define NGRID ((NB + BLOCK - 1) / BLOCK)   // 7813 one-tile blocks (R8: beats grid-stride)
static constexpr float EPSF = 1e-4f;

// R5 two-stage structure + NT loads (streaming path, 6.6 TB/s per fill calibration).
// R10/R11: fuse stage-2 into stage-1 via deterministic last-block finalize.
//   - counter in d_ws[0], zeroed by a 16B hipMemsetAsync node (graph-capturable).
//   - writers: agent-scope relaxed atomic store of partial + ACQ_REL ticket add;
//     the last ticket's acquire reads a value in the release sequence of all
//     prior RMWs -> all partials visible across non-coherent per-XCD L2s (G16).
//   - finalizer reduces partials in FIXED order (grid-stride 256 + shuffle tree)
//     -> deterministic run-to-run, unlike float atomicAdd accumulation.
//   - R11: resubmit after infra-level container failure (no counters returned).
typedef float vf2 __attribute__((ext_vector_type(2)));
typedef float vf4 __attribute__((ext_vector_type(4)));

__device__ __forceinline__ vf2 nt_load2(const float* p) {
    return __builtin_nontemporal_load((const vf2*)p);
}
__device__ __forceinline__ vf4 nt_load4(const float* p) {
    return __builtin_nontemporal_load((const vf4*)p);
}
__device__ __forceinline__ float nt_load1(const float* p) {
    return __builtin_nontemporal_load(p);
}

__global__ __launch_bounds__(256) void gcnl_fused(
    const float* __restrict__ pred_r,
    const float* __restrict__ pred_params,
    const float* __restrict__ pred_corr,
    const float* __restrict__ y_true,
    float* __restrict__ partial,
    unsigned int* __restrict__ counter,
    float* __restrict__ out)
{
    const int i = blockIdx.x * blockDim.x + threadIdx.x;
    float acc = 0.0f;

    if (i < NB) {
        const vf2 rr = nt_load2(pred_r + 2*i);
        const vf2 pa = nt_load2(pred_params + 6*i + 0);
        const vf2 pb = nt_load2(pred_params + 6*i + 2);
        const vf2 pc = nt_load2(pred_params + 6*i + 4);
        const float c0 = nt_load1(pred_corr + 3*i + 0);
        const float c1 = nt_load1(pred_corr + 3*i + 1);
        const float c2 = nt_load1(pred_corr + 3*i + 2);
        const vf4 yt = nt_load4(y_true + 4*i);

        const float r0 = rr.x, r1 = rr.y;
        const float pp0 = pa.x, pp1 = pa.y, pp2 = pb.x;
        const float pp3 = pb.y, pp4 = pc.x, pp5 = pc.y;
        const float r12 = c0, r13 = c1, r23 = c2;
        const float revert = yt.x, Rtop = yt.y, Top = yt.z, Close = yt.w;

        // s = exp(pp) => 1/s = exp(-pp), 0.5*log(s^2) = pp
        const float rtop  = __expf(pp0), is_rtop  = __expf(-pp1);
        const float top   = __expf(pp2), is_top   = __expf(-pp3);
        const float close = __expf(pp4), is_close = __expf(-pp5);

        const float d1 = (rtop  - Rtop ) * is_rtop;
        const float d2 = (top   - Top  ) * is_top;
        const float d3 = (close - Close) * is_close;

        // z = clip((x-u)/s, -3, 3): ndtr/erfinv round-trip collapses (eps-clip outside +-3)
        const float z1 = fminf(fmaxf(-d1, -3.0f), 3.0f);
        const float z2 = fminf(fmaxf(-d2, -3.0f), 3.0f);
        const float z3 = fminf(fmaxf(-d3, -3.0f), 3.0f);

        const float detR = 1.0f + 2.0f*r12*r13*r23 - r12*r12 - r13*r13 - r23*r23;
        const float inv_det = 1.0f / detR;
        const float i00 = (1.0f - r23*r23) * inv_det;
        const float i01 = (r13*r23 - r12) * inv_det;
        const float i02 = (r12*r23 - r13) * inv_det;
        const float i11 = (1.0f - r13*r13) * inv_det;
        const float i12 = (r12*r13 - r23) * inv_det;
        const float i22 = (1.0f - r12*r12) * inv_det;

        const float exp_term = 0.5f*((i00-1.0f)*z1*z1 + (i11-1.0f)*z2*z2 + (i22-1.0f)*z3*z3)
                             + (i01*z1*z2 + i02*z1*z3 + i12*z2*z3);
        const float c_gauss = 0.5f*__logf(fmaxf(detR, EPSF)) + exp_term;
        const float nll = 0.5f*(d1*d1 + d2*d2 + d3*d3) + (pp1 + pp3 + pp5);
        const float copula = revert * (c_gauss + nll);

        // cross-entropy: -logp[sel] = lse - r_sel
        const float m   = fmaxf(r0, r1);
        const float lse = m + __logf(1.0f + __expf(-fabsf(r0 - r1)));
        const float rsel = (revert != 0.0f) ? r1 : r0;

        acc = copula + (lse - rsel);
    }

    // block reduce: wave shuffle + LDS
    #pragma unroll
    for (int off = 32; off > 0; off >>= 1) acc += __shfl_down(acc, off, 64);

    __shared__ float warp_sums[4];
    __shared__ int is_last;
    const int t = threadIdx.x;
    const int lane = t & 63;
    const int wid  = t >> 6;
    if (lane == 0) warp_sums[wid] = acc;
    __syncthreads();
    if (t == 0) {
        const float bs = warp_sums[0] + warp_sums[1] + warp_sums[2] + warp_sums[3];
        // device-scope visible store of this block's partial
        __hip_atomic_store(&partial[blockIdx.x], bs,
                           __ATOMIC_RELAXED, __HIP_MEMORY_SCOPE_AGENT);
        // release our store; acquire everyone else's when we're last
        const unsigned int ticket = __hip_atomic_fetch_add(counter, 1u,
                           __ATOMIC_ACQ_REL, __HIP_MEMORY_SCOPE_AGENT);
        is_last = (ticket == (unsigned int)(NGRID - 1)) ? 1 : 0;
    }
    __syncthreads();   // also orders phase-1 warp_sums reads before phase-2 writes
    if (!is_last) return;

    // finalizer: fixed-order reduction of all partials (deterministic)
    float fa = 0.0f;
    for (int idx = t; idx < NGRID; idx += BLOCK)
        fa += __hip_atomic_load(&partial[idx],
                                __ATOMIC_RELAXED, __HIP_MEMORY_SCOPE_AGENT);

    #pragma unroll
    for (int off = 32; off > 0; off >>= 1) fa += __shfl_down(fa, off, 64);
    if (lane == 0) warp_sums[wid] = fa;
    __syncthreads();
    if (t == 0) {
        out[0] = (warp_sums[0] + warp_sums[1] + warp_sums[2] + warp_sums[3])
               * (1.0f / (float)NB);
    }
}

extern "C" void kernel_launch(void* const* d_in, const int* in_sizes, int n_in,
                              void* d_out, int out_size, void* d_ws, size_t ws_size,
                              hipStream_t stream) {
    const float* pred_r      = (const float*)d_in[0];
    const float* pred_params = (const float*)d_in[1];
    const float* pred_corr   = (const float*)d_in[2];
    const float* y_true      = (const float*)d_in[3];

    unsigned int* counter = (unsigned int*)d_ws;          // bytes [0,4)
    float* partial        = (float*)d_ws + 4;             // bytes [16, 16+4*NGRID)
    float* out            = (float*)d_out;

    // zero ONLY the 16-byte counter slot (workspace is poisoned each iteration;
    // the partial array needs no init -- protocol writes before any read).
    // memset node is graph-capturable; ~1 us vs the ~3-5 us reduce launch it replaces.
    hipMemsetAsync(d_ws, 0, 16, stream);

    hipLaunchKernelGGL(gcnl_fused, dim3(NGRID), dim3(BLOCK), 0, stream,
                       pred_r, pred_params, pred_corr, y_true,
                       partial, counter, out);
}

// Round 3
// 137.383 us; speedup vs baseline: 3.5070x; 3.5070x over previous
//
#include <hip/hip_runtime.h>

#define NB 2000000
#define NB2 (NB/2)                       // rows processed in pairs; NB is even
#define BLOCK 256
#define NGRID ((NB2 + BLOCK - 1) / BLOCK)  // 3907 one-tile blocks
static constexpr float EPSF = 1e-4f;

// R12: REVERT of R10/R11 fusion. Post-mortem: single-counter agent-scope
// ACQ_REL fetch_add serialized at ~48 ns/block (7813 blocks = 372 us) and its
// cache-maintenance ops throttled streaming to 166 GB/s. Two-kernel structure
// restored (R9 baseline: 136.3 us).
// R12 lever: 2 rows/thread so ALL loads are naturally-aligned vf4/vf2
// (9 loads per 2 rows vs 14), halving issue + guard overhead.
// NT loads kept: streaming (non-allocating) path runs 6.6 TB/s vs 4.3 TB/s.
typedef float vf2 __attribute__((ext_vector_type(2)));
typedef float vf4 __attribute__((ext_vector_type(4)));

__device__ __forceinline__ vf2 nt_load2(const float* p) {
    return __builtin_nontemporal_load((const vf2*)p);
}
__device__ __forceinline__ vf4 nt_load4(const float* p) {
    return __builtin_nontemporal_load((const vf4*)p);
}

// One row's loss: copula (masked by revert) + cross-entropy term.
__device__ __forceinline__ float row_loss(
    float r0, float r1,
    float pp0, float pp1, float pp2, float pp3, float pp4, float pp5,
    float r12, float r13, float r23,
    float revert, float Rtop, float Top, float Close)
{
    // s = exp(pp) => 1/s = exp(-pp), 0.5*log(s^2) = pp
    const float rtop  = __expf(pp0), is_rtop  = __expf(-pp1);
    const float top   = __expf(pp2), is_top   = __expf(-pp3);
    const float close = __expf(pp4), is_close = __expf(-pp5);

    const float d1 = (rtop  - Rtop ) * is_rtop;
    const float d2 = (top   - Top  ) * is_top;
    const float d3 = (close - Close) * is_close;

    // z = clip((x-u)/s, -3, 3): ndtr/erfinv round-trip collapses (eps-clip outside +-3)
    const float z1 = fminf(fmaxf(-d1, -3.0f), 3.0f);
    const float z2 = fminf(fmaxf(-d2, -3.0f), 3.0f);
    const float z3 = fminf(fmaxf(-d3, -3.0f), 3.0f);

    const float detR = 1.0f + 2.0f*r12*r13*r23 - r12*r12 - r13*r13 - r23*r23;
    const float inv_det = 1.0f / detR;
    const float i00 = (1.0f - r23*r23) * inv_det;
    const float i01 = (r13*r23 - r12) * inv_det;
    const float i02 = (r12*r23 - r13) * inv_det;
    const float i11 = (1.0f - r13*r13) * inv_det;
    const float i12 = (r12*r13 - r23) * inv_det;
    const float i22 = (1.0f - r12*r12) * inv_det;

    const float exp_term = 0.5f*((i00-1.0f)*z1*z1 + (i11-1.0f)*z2*z2 + (i22-1.0f)*z3*z3)
                         + (i01*z1*z2 + i02*z1*z3 + i12*z2*z3);
    const float c_gauss = 0.5f*__logf(fmaxf(detR, EPSF)) + exp_term;
    const float nll = 0.5f*(d1*d1 + d2*d2 + d3*d3) + (pp1 + pp3 + pp5);
    const float copula = revert * (c_gauss + nll);

    // cross-entropy: -logp[sel] = lse - r_sel
    const float m   = fmaxf(r0, r1);
    const float lse = m + __logf(1.0f + __expf(-fabsf(r0 - r1)));
    const float rsel = (revert != 0.0f) ? r1 : r0;

    return copula + (lse - rsel);
}

__global__ __launch_bounds__(256) void gcnl_main(
    const float* __restrict__ pred_r,
    const float* __restrict__ pred_params,
    const float* __restrict__ pred_corr,
    const float* __restrict__ y_true,
    float* __restrict__ partial)
{
    const int j = blockIdx.x * blockDim.x + threadIdx.x;  // pair index
    float acc = 0.0f;

    if (j < NB2) {
        // rows 2j and 2j+1: every load naturally aligned vf4/vf2
        const vf4 rr = nt_load4(pred_r      + 4*j);        // r[2j], r[2j+1]
        const vf4 p0 = nt_load4(pred_params + 12*j + 0);
        const vf4 p1 = nt_load4(pred_params + 12*j + 4);
        const vf4 p2 = nt_load4(pred_params + 12*j + 8);
        const vf2 ca = nt_load2(pred_corr   + 6*j + 0);
        const vf2 cb = nt_load2(pred_corr   + 6*j + 2);
        const vf2 cc = nt_load2(pred_corr   + 6*j + 4);
        const vf4 ya = nt_load4(y_true      + 8*j + 0);
        const vf4 yb = nt_load4(y_true      + 8*j + 4);

        acc = row_loss(rr.x, rr.y,
                       p0.x, p0.y, p0.z, p0.w, p1.x, p1.y,
                       ca.x, ca.y, cb.x,
                       ya.x, ya.y, ya.z, ya.w)
            + row_loss(rr.z, rr.w,
                       p1.z, p1.w, p2.x, p2.y, p2.z, p2.w,
                       cb.y, cc.x, cc.y,
                       yb.x, yb.y, yb.z, yb.w);
    }

    // block reduce: wave shuffle + LDS, plain store of partial
    #pragma unroll
    for (int off = 32; off > 0; off >>= 1) acc += __shfl_down(acc, off, 64);

    __shared__ float warp_sums[4];
    const int t = threadIdx.x;
    const int lane = t & 63;
    const int wid  = t >> 6;
    if (lane == 0) warp_sums[wid] = acc;
    __syncthreads();
    if (t == 0) {
        partial[blockIdx.x] = warp_sums[0] + warp_sums[1] + warp_sums[2] + warp_sums[3];
    }
}

// Stage 2: one block of 1024 threads sums n partials -> out = s / NB.
__global__ __launch_bounds__(1024) void gcnl_reduce(
    const float* __restrict__ partial, int n, float* __restrict__ out)
{
    const int t = threadIdx.x;
    float acc = 0.0f;
    for (int idx = t; idx < n; idx += 1024) acc += partial[idx];

    #pragma unroll
    for (int off = 32; off > 0; off >>= 1) acc += __shfl_down(acc, off, 64);

    __shared__ float warp_sums[16];
    const int lane = t & 63;
    const int wid  = t >> 6;
    if (lane == 0) warp_sums[wid] = acc;
    __syncthreads();
    if (t == 0) {
        float s = 0.0f;
        #pragma unroll
        for (int k = 0; k < 16; ++k) s += warp_sums[k];
        out[0] = s * (1.0f / (float)NB);
    }
}

extern "C" void kernel_launch(void* const* d_in, const int* in_sizes, int n_in,
                              void* d_out, int out_size, void* d_ws, size_t ws_size,
                              hipStream_t stream) {
    const float* pred_r      = (const float*)d_in[0];
    const float* pred_params = (const float*)d_in[1];
    const float* pred_corr   = (const float*)d_in[2];
    const float* y_true      = (const float*)d_in[3];
    float* partial = (float*)d_ws;   // fully overwritten each call
    float* out = (float*)d_out;

    hipLaunchKernelGGL(gcnl_main, dim3(NGRID), dim3(BLOCK), 0, stream,
                       pred_r, pred_params, pred_corr, y_true, partial);
    hipLaunchKernelGGL(gcnl_reduce, dim3(1), dim3(1024), 0, stream,
                       partial, NGRID, out);
}

// Round 4
// 135.559 us; speedup vs baseline: 3.5542x; 1.0135x over previous
//
#include <hip/hip_runtime.h>

#define NB 2000000
static constexpr float EPSF = 1e-4f;

// R13: restore best-measured variant (R0/R9 form, 136.3 us) verbatim.
// Session ledger:
//  - R10/R11 fused last-block-finalize: REFUTED. Single-counter agent-scope
//    ACQ_REL fetch_add serializes ~48 ns/block (7813 blocks -> 372 us) and its
//    cache maintenance throttles streaming to 166 GB/s. Two-kernel wins.
//  - R12 2-rows/thread all-vf4: neutral-to-negative (137.4 vs 136.3) --
//    halving block count loses TLP (confirms R8: 7813 one-tile blocks best);
//    strided param loads were already L1-absorbed.
//  - NT loads: streaming (non-allocating) path 6.6 TB/s vs 4.3 TB/s allocating.
// Roofline: 120 MB mandatory reads @6.6 TB/s = 18.2 us + ~4 us reduce; total
// dur dominated by fixed harness poison fills (40.5 us each @ 82% peak).
typedef float vf2 __attribute__((ext_vector_type(2)));
typedef float vf4 __attribute__((ext_vector_type(4)));

__device__ __forceinline__ vf2 nt_load2(const float* p) {
    return __builtin_nontemporal_load((const vf2*)p);
}
__device__ __forceinline__ vf4 nt_load4(const float* p) {
    return __builtin_nontemporal_load((const vf4*)p);
}
__device__ __forceinline__ float nt_load1(const float* p) {
    return __builtin_nontemporal_load(p);
}

__global__ __launch_bounds__(256) void gcnl_main(
    const float* __restrict__ pred_r,
    const float* __restrict__ pred_params,
    const float* __restrict__ pred_corr,
    const float* __restrict__ y_true,
    float* __restrict__ partial)
{
    const int i = blockIdx.x * blockDim.x + threadIdx.x;
    float acc = 0.0f;

    if (i < NB) {
        const vf2 rr = nt_load2(pred_r + 2*i);
        const vf2 pa = nt_load2(pred_params + 6*i + 0);
        const vf2 pb = nt_load2(pred_params + 6*i + 2);
        const vf2 pc = nt_load2(pred_params + 6*i + 4);
        const float c0 = nt_load1(pred_corr + 3*i + 0);
        const float c1 = nt_load1(pred_corr + 3*i + 1);
        const float c2 = nt_load1(pred_corr + 3*i + 2);
        const vf4 yt = nt_load4(y_true + 4*i);

        const float r0 = rr.x, r1 = rr.y;
        const float pp0 = pa.x, pp1 = pa.y, pp2 = pb.x;
        const float pp3 = pb.y, pp4 = pc.x, pp5 = pc.y;
        const float r12 = c0, r13 = c1, r23 = c2;
        const float revert = yt.x, Rtop = yt.y, Top = yt.z, Close = yt.w;

        // s = exp(pp) => 1/s = exp(-pp), 0.5*log(s^2) = pp
        const float rtop  = __expf(pp0), is_rtop  = __expf(-pp1);
        const float top   = __expf(pp2), is_top   = __expf(-pp3);
        const float close = __expf(pp4), is_close = __expf(-pp5);

        const float d1 = (rtop  - Rtop ) * is_rtop;
        const float d2 = (top   - Top  ) * is_top;
        const float d3 = (close - Close) * is_close;

        // z = clip((x-u)/s, -3, 3): ndtr/erfinv round-trip collapses (eps-clip outside +-3)
        const float z1 = fminf(fmaxf(-d1, -3.0f), 3.0f);
        const float z2 = fminf(fmaxf(-d2, -3.0f), 3.0f);
        const float z3 = fminf(fmaxf(-d3, -3.0f), 3.0f);

        const float detR = 1.0f + 2.0f*r12*r13*r23 - r12*r12 - r13*r13 - r23*r23;
        const float inv_det = 1.0f / detR;
        const float i00 = (1.0f - r23*r23) * inv_det;
        const float i01 = (r13*r23 - r12) * inv_det;
        const float i02 = (r12*r23 - r13) * inv_det;
        const float i11 = (1.0f - r13*r13) * inv_det;
        const float i12 = (r12*r13 - r23) * inv_det;
        const float i22 = (1.0f - r12*r12) * inv_det;

        const float exp_term = 0.5f*((i00-1.0f)*z1*z1 + (i11-1.0f)*z2*z2 + (i22-1.0f)*z3*z3)
                             + (i01*z1*z2 + i02*z1*z3 + i12*z2*z3);
        const float c_gauss = 0.5f*__logf(fmaxf(detR, EPSF)) + exp_term;
        const float nll = 0.5f*(d1*d1 + d2*d2 + d3*d3) + (pp1 + pp3 + pp5);
        const float copula = revert * (c_gauss + nll);

        // cross-entropy: -logp[sel] = lse - r_sel
        const float m   = fmaxf(r0, r1);
        const float lse = m + __logf(1.0f + __expf(-fabsf(r0 - r1)));
        const float rsel = (revert != 0.0f) ? r1 : r0;

        acc = copula + (lse - rsel);
    }

    // block reduce: wave shuffle + LDS, plain store of partial
    #pragma unroll
    for (int off = 32; off > 0; off >>= 1) acc += __shfl_down(acc, off, 64);

    __shared__ float warp_sums[4];
    const int t = threadIdx.x;
    const int lane = t & 63;
    const int wid  = t >> 6;
    if (lane == 0) warp_sums[wid] = acc;
    __syncthreads();
    if (t == 0) {
        partial[blockIdx.x] = warp_sums[0] + warp_sums[1] + warp_sums[2] + warp_sums[3];
    }
}

// Stage 2: one block of 1024 threads sums n partials -> out = s / NB.
__global__ __launch_bounds__(1024) void gcnl_reduce(
    const float* __restrict__ partial, int n, float* __restrict__ out)
{
    const int t = threadIdx.x;
    float acc = 0.0f;
    for (int idx = t; idx < n; idx += 1024) acc += partial[idx];

    #pragma unroll
    for (int off = 32; off > 0; off >>= 1) acc += __shfl_down(acc, off, 64);

    __shared__ float warp_sums[16];
    const int lane = t & 63;
    const int wid  = t >> 6;
    if (lane == 0) warp_sums[wid] = acc;
    __syncthreads();
    if (t == 0) {
        float s = 0.0f;
        #pragma unroll
        for (int k = 0; k < 16; ++k) s += warp_sums[k];
        out[0] = s * (1.0f / (float)NB);
    }
}

extern "C" void kernel_launch(void* const* d_in, const int* in_sizes, int n_in,
                              void* d_out, int out_size, void* d_ws, size_t ws_size,
                              hipStream_t stream) {
    const float* pred_r      = (const float*)d_in[0];
    const float* pred_params = (const float*)d_in[1];
    const float* pred_corr   = (const float*)d_in[2];
    const float* y_true      = (const float*)d_in[3];
    float* partial = (float*)d_ws;   // fully overwritten each call
    float* out = (float*)d_out;

    const int block = 256;
    const int grid = (NB + block - 1) / block;  // 7813 blocks, 1 tile each
    hipLaunchKernelGGL(gcnl_main, dim3(grid), dim3(block), 0, stream,
                       pred_r, pred_params, pred_corr, y_true, partial);
    hipLaunchKernelGGL(gcnl_reduce, dim3(1), dim3(1024), 0, stream,
                       partial, grid, out);
}